// Round 2
// baseline (651.134 us; speedup 1.0000x reference)
//
#include <hip/hip_runtime.h>
#include <cstdint>
#include <cstddef>

#define NN 100000
#define NP 100096          // rows padded to multiple of 64
#define EE 1600000
#define ET 1700000         // EE + NN self-loops
#define NBKT 196           // ceil(NN/512) dst-range buckets
#define TILE 2048          // edges per k_bucket block
#define STAT_BLOCKS 400
#define EWG 256            // dst nodes per k_ew block

typedef short  bf16x8 __attribute__((ext_vector_type(8)));
typedef float  f32x4  __attribute__((ext_vector_type(4)));

__device__ __forceinline__ float leaky(float v) { return v > 0.f ? v : 0.2f * v; }

__device__ __forceinline__ unsigned short f2bf(float f) {
    unsigned int x = __builtin_bit_cast(unsigned int, f);
    x += 0x7FFFu + ((x >> 16) & 1u);   // RNE
    return (unsigned short)(x >> 16);
}
__device__ __forceinline__ unsigned int pk2(float lo, float hi) {
    return ((unsigned int)f2bf(hi) << 16) | (unsigned int)f2bf(lo);
}
__device__ __forceinline__ float bflo(unsigned int u) {
    return __builtin_bit_cast(float, u << 16);
}
__device__ __forceinline__ float bfhi(unsigned int u) {
    return __builtin_bit_cast(float, u & 0xFFFF0000u);
}

// ======================= CSR build via 2-level bucket sort =======================
// bucket = dst >> 9 (512 dsts per bucket); packed edge = (dst&511)<<17 | src

__global__ void k_bcount(const int* __restrict__ ei, int* __restrict__ btot) {
    __shared__ int h[256];
    int t = threadIdx.x;
    h[t] = 0;
    __syncthreads();
    for (int e = blockIdx.x * 256 + t; e < ET; e += 256 * 256) {
        int d = (e < EE) ? ei[EE + e] : (e - EE);
        atomicAdd(&h[d >> 9], 1);
    }
    __syncthreads();
    if (h[t]) atomicAdd(&btot[t], h[t]);
}

__global__ void k_bscan(const int* __restrict__ btot, int* __restrict__ bstart,
                        int* __restrict__ bcur, int* __restrict__ off) {
    __shared__ int s[256];
    int t = threadIdx.x;
    int v = (t < NBKT) ? btot[t] : 0;
    s[t] = v;
    __syncthreads();
    for (int o = 1; o < 256; o <<= 1) {
        int a = (t >= o) ? s[t - o] : 0;
        __syncthreads();
        s[t] += a;
        __syncthreads();
    }
    int ex = s[t] - v;
    if (t <= NBKT) bstart[t] = (t < NBKT) ? ex : ET;
    if (t == NBKT - 1) bstart[NBKT] = s[t];   // == ET
    bcur[t] = ex;
    if (t == 0) off[NN] = ET;
}

__global__ __launch_bounds__(256) void k_bucket(
    const int* __restrict__ ei, int* __restrict__ bcur, unsigned int* __restrict__ bucketed)
{
    __shared__ int h4[4][256], woff[4][256], loff[256], gbase[256], sc[256];
    __shared__ unsigned int stage[TILE];
    __shared__ int gaddr[TILE];
    __shared__ int stot_s;
    const int t = threadIdx.x;
    const int w = t >> 6;
    const int e0 = blockIdx.x * TILE;

    h4[0][t] = 0; h4[1][t] = 0; h4[2][t] = 0; h4[3][t] = 0;
    __syncthreads();

    unsigned int pk[TILE / 256];
    int bk[TILE / 256];
#pragma unroll
    for (int i = 0; i < TILE / 256; ++i) {
        int e = e0 + i * 256 + t;
        bk[i] = -1;
        if (e < ET) {
            int s, d;
            if (e < EE) { s = ei[e]; d = ei[EE + e]; } else { s = e - EE; d = s; }
            bk[i] = d >> 9;
            pk[i] = ((unsigned int)(d & 511) << 17) | (unsigned int)s;
            atomicAdd(&h4[w][bk[i]], 1);
        }
    }
    __syncthreads();

    // per-bucket totals + inclusive scan
    int h0 = h4[0][t], h1 = h4[1][t], h2 = h4[2][t], h3 = h4[3][t];
    int tot = h0 + h1 + h2 + h3;
    sc[t] = tot;
    __syncthreads();
    for (int o = 1; o < 256; o <<= 1) {
        int a = (t >= o) ? sc[t - o] : 0;
        __syncthreads();
        sc[t] += a;
        __syncthreads();
    }
    int lo = sc[t] - tot;
    loff[t] = lo;
    woff[0][t] = lo;
    woff[1][t] = lo + h0;
    woff[2][t] = lo + h0 + h1;
    woff[3][t] = lo + h0 + h1 + h2;
    if (t < NBKT && tot) gbase[t] = atomicAdd(&bcur[t], tot);
    if (t == 255) stot_s = sc[255];
    h4[0][t] = 0; h4[1][t] = 0; h4[2][t] = 0; h4[3][t] = 0;
    __syncthreads();

    // rank (per-wave counters -> 4x less LDS-atomic contention) + stage
#pragma unroll
    for (int i = 0; i < TILE / 256; ++i) {
        if (bk[i] >= 0) {
            int b = bk[i];
            int r = woff[w][b] + atomicAdd(&h4[w][b], 1);
            stage[r] = pk[i];
            gaddr[r] = gbase[b] + (r - loff[b]);
        }
    }
    __syncthreads();

    const int stot = stot_s;
    for (int j = t; j < stot; j += 256)
        bucketed[gaddr[j]] = stage[j];
}

__global__ __launch_bounds__(256) void k_csr(
    const unsigned int* __restrict__ bucketed, const int* __restrict__ bstart,
    int* __restrict__ off, int* __restrict__ srcs)
{
    __shared__ int h[512], sc2[512], c2[512], sp[256];
    const int t = threadIdx.x;
    const int b = blockIdx.x;
    const int beg = bstart[b], end = bstart[b + 1];
    const int cnt = end - beg;

    h[t] = 0; h[t + 256] = 0; c2[t] = 0; c2[t + 256] = 0;
    __syncthreads();
    for (int i = t; i < cnt; i += 256)
        atomicAdd(&h[bucketed[beg + i] >> 17], 1);
    __syncthreads();

    int a0 = h[2 * t], a1 = h[2 * t + 1];
    sp[t] = a0 + a1;
    __syncthreads();
    for (int o = 1; o < 256; o <<= 1) {
        int a = (t >= o) ? sp[t - o] : 0;
        __syncthreads();
        sp[t] += a;
        __syncthreads();
    }
    int ep = sp[t] - (a0 + a1);
    sc2[2 * t] = ep;
    sc2[2 * t + 1] = ep + a0;
    __syncthreads();

    const int d0 = b << 9;
#pragma unroll
    for (int k = t; k < 512; k += 256) {
        int d = d0 + k;
        if (d < NN) off[d] = beg + sc2[k];
    }

    for (int i = t; i < cnt; i += 256) {
        unsigned int v = bucketed[beg + i];
        int ld = v >> 17;
        int r = atomicAdd(&c2[ld], 1);
        srcs[beg + sc2[ld] + r] = (int)(v & 0x1FFFFu);
    }
}

// ======================= weight conversion (all 3 layers, one launch) =======================
__global__ void k_cvtw3(const float* __restrict__ W0, const float* __restrict__ W1,
                        const float* __restrict__ W2, unsigned short* __restrict__ Wb) {
    int i = blockIdx.x * 256 + threadIdx.x;   // 49152 elements
    const float* W = (i < 16384) ? W0 : (i < 32768) ? W1 : W2;
    Wb[i] = f2bf(W[i & 16383]);
}

// ======================= MFMA GEMM: H = X @ W^T, fused BN-affine/relu/cvt + AS/AD ===========
// MODE 0: plain fp32 read; MODE 1: BN affine (computed in-kernel from raw stats) + relu
template<int MODE>
__global__ __launch_bounds__(256) void k_mfma(
    const float* __restrict__ Xf, const unsigned short* __restrict__ Wb,
    const float* __restrict__ gsum, const float* __restrict__ gsq,
    const float* __restrict__ gamma, const float* __restrict__ beta,
    const float* __restrict__ asrc, const float* __restrict__ adst,
    unsigned short* __restrict__ Hb, float* __restrict__ AS, float* __restrict__ AD)
{
    __shared__ float hst[4][16][132];
    __shared__ float scale_s[128], shift_s[128];
    const int t    = threadIdx.x;
    const int w    = t >> 6;
    const int lane = t & 63;
    const int c    = lane & 15;
    const int q    = lane >> 4;
    const int r0   = blockIdx.x * 64 + w * 16;
    const int row  = r0 + c;

    if (MODE) {
        // BN final stage fused here: per-column affine from raw sums (once per block)
        if (t < 128) {
            float mu  = gsum[t] * (1.f / NN);
            float var = gsq[t] * (1.f / NN) - mu * mu;
            float sc  = gamma[t] * rsqrtf(var + 1e-5f);
            scale_s[t] = sc;
            shift_s[t] = beta[t] - mu * sc;
        }
        __syncthreads();
    }

    union { uint4 u; bf16x8 v; } Af[4];
    if (row < NN) {
        const float* xp = Xf + ((size_t)row << 7) + (q << 3);
#pragma unroll
        for (int k0 = 0; k0 < 4; ++k0) {
            float4 a = *(const float4*)(xp + (k0 << 5));
            float4 b = *(const float4*)(xp + (k0 << 5) + 4);
            if (MODE) {
                const int kb = (k0 << 5) + (q << 3);
                float4 sA = *(const float4*)&scale_s[kb];
                float4 sB = *(const float4*)&scale_s[kb + 4];
                float4 hA = *(const float4*)&shift_s[kb];
                float4 hB = *(const float4*)&shift_s[kb + 4];
                a.x = fmaxf(0.f, fmaf(a.x, sA.x, hA.x));
                a.y = fmaxf(0.f, fmaf(a.y, sA.y, hA.y));
                a.z = fmaxf(0.f, fmaf(a.z, sA.z, hA.z));
                a.w = fmaxf(0.f, fmaf(a.w, sA.w, hA.w));
                b.x = fmaxf(0.f, fmaf(b.x, sB.x, hB.x));
                b.y = fmaxf(0.f, fmaf(b.y, sB.y, hB.y));
                b.z = fmaxf(0.f, fmaf(b.z, sB.z, hB.z));
                b.w = fmaxf(0.f, fmaf(b.w, sB.w, hB.w));
            }
            Af[k0].u.x = pk2(a.x, a.y);
            Af[k0].u.y = pk2(a.z, a.w);
            Af[k0].u.z = pk2(b.x, b.y);
            Af[k0].u.w = pk2(b.z, b.w);
        }
    } else {
#pragma unroll
        for (int k0 = 0; k0 < 4; ++k0) Af[k0].u = make_uint4(0, 0, 0, 0);
    }

    f32x4 acc[8];
#pragma unroll
    for (int nt = 0; nt < 8; ++nt) acc[nt] = (f32x4){0.f, 0.f, 0.f, 0.f};

#pragma unroll
    for (int nt = 0; nt < 8; ++nt) {
        union { uint4 u; bf16x8 v; } Bf[4];
        const size_t bbase = ((size_t)(nt * 16 + c) << 7) + (q << 3);
#pragma unroll
        for (int k0 = 0; k0 < 4; ++k0)
            Bf[k0].u = *(const uint4*)(Wb + bbase + (k0 << 5));
#pragma unroll
        for (int k0 = 0; k0 < 4; ++k0)
            acc[nt] = __builtin_amdgcn_mfma_f32_16x16x32_bf16(Af[k0].v, Bf[k0].v, acc[nt], 0, 0, 0);
    }

    // fused AS/AD; C/D layout col=lane&15, row=q*4+reg
    float ps[4] = {0.f, 0.f, 0.f, 0.f}, pd[4] = {0.f, 0.f, 0.f, 0.f};
#pragma unroll
    for (int nt = 0; nt < 8; ++nt) {
        float av = asrc[nt * 16 + c];
        float dv = adst[nt * 16 + c];
#pragma unroll
        for (int r = 0; r < 4; ++r) {
            ps[r] = fmaf(acc[nt][r], av, ps[r]);
            pd[r] = fmaf(acc[nt][r], dv, pd[r]);
        }
    }
#pragma unroll
    for (int m = 1; m < 16; m <<= 1) {
#pragma unroll
        for (int r = 0; r < 4; ++r) { ps[r] += __shfl_xor(ps[r], m); pd[r] += __shfl_xor(pd[r], m); }
    }
    if (c == 0) {
#pragma unroll
        for (int r = 0; r < 4; ++r) {
            int grow = r0 + q * 4 + r;
            if (grow < NN) { AS[grow] = ps[r]; AD[grow] = pd[r]; }
        }
    }

    // H store via LDS transpose, pk-cvt to bf16
#pragma unroll
    for (int nt = 0; nt < 8; ++nt)
#pragma unroll
        for (int r = 0; r < 4; ++r)
            hst[w][q * 4 + r][nt * 16 + c] = acc[nt][r];
    __syncthreads();
    {
        const int orow = lane >> 2, seg = lane & 3;
        const int grow = r0 + orow;
        if (grow < NN) {
#pragma unroll
            for (int i = 0; i < 4; ++i) {
                float4 a = *(const float4*)&hst[w][orow][seg * 32 + i * 8];
                float4 b = *(const float4*)&hst[w][orow][seg * 32 + i * 8 + 4];
                uint4 o;
                o.x = pk2(a.x, a.y); o.y = pk2(a.z, a.w);
                o.z = pk2(b.x, b.y); o.w = pk2(b.z, b.w);
                *(uint4*)(Hb + ((size_t)grow << 7) + seg * 32 + i * 8) = o;
            }
        }
    }
}

// ======================= edge weights (edge-parallel; hoists gather+exp off k_agg's path) ====
// one thread per edge; dst recovered via LDS off-table binary search (edges are dst-sorted)
__global__ __launch_bounds__(256) void k_ew(
    const int* __restrict__ off, const int* __restrict__ srcs,
    const float* __restrict__ AS, const float* __restrict__ AD,
    float* __restrict__ w)
{
    __shared__ int soff[EWG + 1];
    __shared__ float sad[EWG];
    const int t  = threadIdx.x;
    const int n0 = blockIdx.x * EWG;

    for (int k = t; k <= EWG; k += 256) {
        int n = n0 + k;
        soff[k] = off[n < NN ? n : NN];
    }
    {
        int n = n0 + t;
        sad[t] = (n < NN) ? AD[n] : 0.f;
    }
    __syncthreads();

    const int ebeg = soff[0], eend = soff[EWG];
    for (int p = ebeg + t; p < eend; p += 256) {
        // binary search: find l with soff[l] <= p < soff[l+1]
        int lo = 0, hi = EWG;
        while (hi - lo > 1) {
            int mid = (lo + hi) >> 1;
            if (p >= soff[mid]) lo = mid; else hi = mid;
        }
        float e = AS[srcs[p]] + sad[lo];
        e = (e > 0.f) ? e : 0.2f * e;
        w[p] = __expf(e);
    }
}

// ======================= per-dst softmax + aggregation (single pass) =======================
// v3: weights precomputed by k_ew -> per-tile head is just two coalesced loads feeding
// straight into Hb gather rounds. Inner loop back to v1 structure (compiler pipelines it).
__global__ __launch_bounds__(256) void k_agg(
    const int* __restrict__ off, const int* __restrict__ srcs,
    const float* __restrict__ w, const unsigned short* __restrict__ Hb,
    const float* __restrict__ bias, float* __restrict__ OUT)
{
    __shared__ uint2 s_e[4][64];
    const int wid  = threadIdx.x >> 6;
    const int lane = threadIdx.x & 63;
    const int g    = lane >> 4;     // edge subgroup 0..3
    const int x16  = lane & 15;     // 16-lane column group
    const int n    = blockIdx.x * 4 + wid;
    const int beg = off[n], end = off[n + 1];

    float acc[8];
#pragma unroll
    for (int i = 0; i < 8; ++i) acc[i] = 0.f;
    float den = 0.f;

    for (int base = beg; base < end; base += 64) {
        int cnt = end - base; if (cnt > 64) cnt = 64;
        float wgt = 0.f; int s = 0;
        if (lane < cnt) {
            s   = srcs[base + lane];
            wgt = w[base + lane];
        }
        s_e[wid][lane] = make_uint2((unsigned int)s, __builtin_bit_cast(unsigned int, wgt));
        den += wgt;
        int rounds = (cnt + 3) >> 2;
        for (int j = 0; j < rounds; ++j) {
            uint2 ew = s_e[wid][(j << 2) + g];
            float wq = __builtin_bit_cast(float, ew.y);
            uint4 u = *((const uint4*)(Hb + ((size_t)ew.x << 7)) + x16);
            acc[0] = fmaf(wq, bflo(u.x), acc[0]);
            acc[1] = fmaf(wq, bfhi(u.x), acc[1]);
            acc[2] = fmaf(wq, bflo(u.y), acc[2]);
            acc[3] = fmaf(wq, bfhi(u.y), acc[3]);
            acc[4] = fmaf(wq, bflo(u.z), acc[4]);
            acc[5] = fmaf(wq, bfhi(u.z), acc[5]);
            acc[6] = fmaf(wq, bflo(u.w), acc[6]);
            acc[7] = fmaf(wq, bfhi(u.w), acc[7]);
        }
    }

    // reduce partial sums across the 4 edge subgroups; den across all 64 lanes
#pragma unroll
    for (int i = 0; i < 8; ++i) {
        acc[i] += __shfl_xor(acc[i], 16);
        acc[i] += __shfl_xor(acc[i], 32);
    }
#pragma unroll
    for (int o = 32; o; o >>= 1) den += __shfl_xor(den, o);
    float inv = 1.f / den;

    if (g == 0) {
        float4 b1 = *(const float4*)&bias[x16 << 3];
        float4 b2 = *(const float4*)&bias[(x16 << 3) + 4];
        float4 o1 = make_float4(fmaf(acc[0], inv, b1.x), fmaf(acc[1], inv, b1.y),
                                fmaf(acc[2], inv, b1.z), fmaf(acc[3], inv, b1.w));
        float4 o2 = make_float4(fmaf(acc[4], inv, b2.x), fmaf(acc[5], inv, b2.y),
                                fmaf(acc[6], inv, b2.z), fmaf(acc[7], inv, b2.w));
        float* op = OUT + ((size_t)n << 7) + (x16 << 3);
        *(float4*)op = o1;
        *(float4*)(op + 4) = o2;
    }
}

// ======================= batchnorm stats (raw sums; affine folded into k_mfma) ===========
__global__ void k_colsum(const float* __restrict__ Xf, float* __restrict__ gsum, float* __restrict__ gsq) {
    __shared__ float ls[256], lq[256];
    int t = threadIdx.x;
    int c = t & 127, half = t >> 7;
    float s = 0.f, q = 0.f;
    for (int r = blockIdx.x * 2 + half; r < NN; r += STAT_BLOCKS * 2) {
        float v = Xf[(size_t)r * 128 + c];
        s += v; q += v * v;
    }
    ls[t] = s; lq[t] = q;
    __syncthreads();
    if (t < 128) {
        atomicAdd(&gsum[c], ls[t] + ls[t + 128]);
        atomicAdd(&gsq[c],  lq[t] + lq[t + 128]);
    }
}

extern "C" void kernel_launch(void* const* d_in, const int* in_sizes, int n_in,
                              void* d_out, int out_size, void* d_ws, size_t ws_size,
                              hipStream_t stream)
{
    const float* x  = (const float*)d_in[0];
    const int*   ei = (const int*)d_in[1];
    const float* Wm[3]  = {(const float*)d_in[2], (const float*)d_in[6],  (const float*)d_in[10]};
    const float* Asr[3] = {(const float*)d_in[3], (const float*)d_in[7],  (const float*)d_in[11]};
    const float* Ads[3] = {(const float*)d_in[4], (const float*)d_in[8],  (const float*)d_in[12]};
    const float* Bs[3]  = {(const float*)d_in[5], (const float*)d_in[9],  (const float*)d_in[13]};
    const float* gam[2] = {(const float*)d_in[14], (const float*)d_in[16]};
    const float* bet[2] = {(const float*)d_in[15], (const float*)d_in[17]};

    char* p = (char*)d_ws;
    auto carve = [&](size_t bytes) -> char* {
        char* r = p;
        p += (bytes + 255) & ~(size_t)255;
        return r;
    };
    int*   off_   = (int*)carve((size_t)(NN + 1) * 4);
    int*   srcs   = (int*)carve((size_t)ET * 4);
    unsigned int* bucketed = (unsigned int*)carve((size_t)ET * 4);  // reused as w[] after k_csr
    int*   btot   = (int*)carve(256 * 4);          // 1024 B, followed immediately by...
    float* gstat  = (float*)carve(4 * 128 * 4);    // gsum0,gsq0,gsum1,gsq1 (2048 B) — one memset
    int*   bstart = (int*)carve(260 * 4);
    int*   bcur   = (int*)carve(256 * 4);
    unsigned short* Hb  = (unsigned short*)carve((size_t)NP * 128 * 2);
    unsigned short* Wb  = (unsigned short*)carve((size_t)3 * 16384 * 2);  // contiguous 3 layers
    float* AS    = (float*)carve((size_t)NN * 4);
    float* AD    = (float*)carve((size_t)NN * 4);

    float* wE   = (float*)bucketed;   // edge-weight buffer aliases dead bucketed[]
    float* OUTf = (float*)d_out;      // fp32 intermediate lives in d_out (fully rewritten)

    // zero btot + all 4 stat vectors in one shot (they are carved adjacently)
    (void)hipMemsetAsync(btot, 0, 256 * 4 + 4 * 128 * 4, stream);

    // CSR build (bucket sort)
    k_bcount<<<256, 256, 0, stream>>>(ei, btot);
    k_bscan<<<1, 256, 0, stream>>>(btot, bstart, bcur, off_);
    k_bucket<<<(ET + TILE - 1) / TILE, 256, 0, stream>>>(ei, bcur, bucketed);
    k_csr<<<NBKT, 256, 0, stream>>>(bucketed, bstart, off_, srcs);

    // weight conversions (single launch)
    k_cvtw3<<<192, 256, 0, stream>>>(Wm[0], Wm[1], Wm[2], Wb);

    const int MFMA_GRID = NP / 64;
    const int EW_GRID   = (NN + EWG - 1) / EWG;

    // layer 0
    k_mfma<0><<<MFMA_GRID, 256, 0, stream>>>(x, Wb, nullptr, nullptr, nullptr, nullptr,
                                             Asr[0], Ads[0], Hb, AS, AD);
    k_ew<<<EW_GRID, 256, 0, stream>>>(off_, srcs, AS, AD, wE);
    k_agg<<<NN / 4, 256, 0, stream>>>(off_, srcs, wE, Hb, Bs[0], OUTf);
    k_colsum<<<STAT_BLOCKS, 256, 0, stream>>>(OUTf, gstat, gstat + 128);

    // layer 1 (BN affine computed inside k_mfma from raw sums)
    k_mfma<1><<<MFMA_GRID, 256, 0, stream>>>(OUTf, Wb + 16384, gstat, gstat + 128,
                                             gam[0], bet[0], Asr[1], Ads[1], Hb, AS, AD);
    k_ew<<<EW_GRID, 256, 0, stream>>>(off_, srcs, AS, AD, wE);
    k_agg<<<NN / 4, 256, 0, stream>>>(off_, srcs, wE, Hb, Bs[1], OUTf);
    k_colsum<<<STAT_BLOCKS, 256, 0, stream>>>(OUTf, gstat + 256, gstat + 384);

    // layer 2 (k_agg writes final fp32 output into d_out)
    k_mfma<1><<<MFMA_GRID, 256, 0, stream>>>(OUTf, Wb + 32768, gstat + 256, gstat + 384,
                                             gam[1], bet[1], Asr[2], Ads[2], Hb, AS, AD);
    k_ew<<<EW_GRID, 256, 0, stream>>>(off_, srcs, AS, AD, wE);
    k_agg<<<NN / 4, 256, 0, stream>>>(off_, srcs, wE, Hb, Bs[2], OUTf);
}

// Round 3
// 602.616 us; speedup vs baseline: 1.0805x; 1.0805x over previous
//
#include <hip/hip_runtime.h>
#include <cstdint>
#include <cstddef>

#define NN 100000
#define NP 100096          // rows padded to multiple of 64
#define EE 1600000
#define ET 1700000         // EE + NN self-loops
#define NBKT 196           // ceil(NN/512) dst-range buckets
#define TILE 2048          // edges per k_bucket block
#define STAT_BLOCKS 400

typedef short  bf16x8 __attribute__((ext_vector_type(8)));
typedef float  f32x4  __attribute__((ext_vector_type(4)));

__device__ __forceinline__ float leaky(float v) { return v > 0.f ? v : 0.2f * v; }

__device__ __forceinline__ unsigned short f2bf(float f) {
    unsigned int x = __builtin_bit_cast(unsigned int, f);
    x += 0x7FFFu + ((x >> 16) & 1u);   // RNE
    return (unsigned short)(x >> 16);
}
__device__ __forceinline__ unsigned int pk2(float lo, float hi) {
    return ((unsigned int)f2bf(hi) << 16) | (unsigned int)f2bf(lo);
}
__device__ __forceinline__ float bflo(unsigned int u) {
    return __builtin_bit_cast(float, u << 16);
}
__device__ __forceinline__ float bfhi(unsigned int u) {
    return __builtin_bit_cast(float, u & 0xFFFF0000u);
}

// ======================= CSR build via 2-level bucket sort =======================
// bucket = dst >> 9 (512 dsts per bucket); packed edge = (dst&511)<<17 | src

__global__ void k_bcount(const int* __restrict__ ei, int* __restrict__ btot) {
    __shared__ int h[256];
    int t = threadIdx.x;
    h[t] = 0;
    __syncthreads();
    for (int e = blockIdx.x * 256 + t; e < ET; e += 256 * 256) {
        int d = (e < EE) ? ei[EE + e] : (e - EE);
        atomicAdd(&h[d >> 9], 1);
    }
    __syncthreads();
    if (h[t]) atomicAdd(&btot[t], h[t]);
}

__global__ void k_bscan(const int* __restrict__ btot, int* __restrict__ bstart,
                        int* __restrict__ bcur, int* __restrict__ off) {
    __shared__ int s[256];
    int t = threadIdx.x;
    int v = (t < NBKT) ? btot[t] : 0;
    s[t] = v;
    __syncthreads();
    for (int o = 1; o < 256; o <<= 1) {
        int a = (t >= o) ? s[t - o] : 0;
        __syncthreads();
        s[t] += a;
        __syncthreads();
    }
    int ex = s[t] - v;
    if (t <= NBKT) bstart[t] = (t < NBKT) ? ex : ET;
    if (t == NBKT - 1) bstart[NBKT] = s[t];   // == ET
    bcur[t] = ex;
    if (t == 0) off[NN] = ET;
}

__global__ __launch_bounds__(256) void k_bucket(
    const int* __restrict__ ei, int* __restrict__ bcur, unsigned int* __restrict__ bucketed)
{
    __shared__ int h4[4][256], woff[4][256], loff[256], gbase[256], sc[256];
    __shared__ unsigned int stage[TILE];
    __shared__ int gaddr[TILE];
    __shared__ int stot_s;
    const int t = threadIdx.x;
    const int w = t >> 6;
    const int e0 = blockIdx.x * TILE;

    h4[0][t] = 0; h4[1][t] = 0; h4[2][t] = 0; h4[3][t] = 0;
    __syncthreads();

    unsigned int pk[TILE / 256];
    int bk[TILE / 256];
#pragma unroll
    for (int i = 0; i < TILE / 256; ++i) {
        int e = e0 + i * 256 + t;
        bk[i] = -1;
        if (e < ET) {
            int s, d;
            if (e < EE) { s = ei[e]; d = ei[EE + e]; } else { s = e - EE; d = s; }
            bk[i] = d >> 9;
            pk[i] = ((unsigned int)(d & 511) << 17) | (unsigned int)s;
            atomicAdd(&h4[w][bk[i]], 1);
        }
    }
    __syncthreads();

    // per-bucket totals + inclusive scan
    int h0 = h4[0][t], h1 = h4[1][t], h2 = h4[2][t], h3 = h4[3][t];
    int tot = h0 + h1 + h2 + h3;
    sc[t] = tot;
    __syncthreads();
    for (int o = 1; o < 256; o <<= 1) {
        int a = (t >= o) ? sc[t - o] : 0;
        __syncthreads();
        sc[t] += a;
        __syncthreads();
    }
    int lo = sc[t] - tot;
    loff[t] = lo;
    woff[0][t] = lo;
    woff[1][t] = lo + h0;
    woff[2][t] = lo + h0 + h1;
    woff[3][t] = lo + h0 + h1 + h2;
    if (t < NBKT && tot) gbase[t] = atomicAdd(&bcur[t], tot);
    if (t == 255) stot_s = sc[255];
    h4[0][t] = 0; h4[1][t] = 0; h4[2][t] = 0; h4[3][t] = 0;
    __syncthreads();

    // rank (per-wave counters -> 4x less LDS-atomic contention) + stage
#pragma unroll
    for (int i = 0; i < TILE / 256; ++i) {
        if (bk[i] >= 0) {
            int b = bk[i];
            int r = woff[w][b] + atomicAdd(&h4[w][b], 1);
            stage[r] = pk[i];
            gaddr[r] = gbase[b] + (r - loff[b]);
        }
    }
    __syncthreads();

    const int stot = stot_s;
    for (int j = t; j < stot; j += 256)
        bucketed[gaddr[j]] = stage[j];
}

__global__ __launch_bounds__(256) void k_csr(
    const unsigned int* __restrict__ bucketed, const int* __restrict__ bstart,
    int* __restrict__ off, int* __restrict__ srcs)
{
    __shared__ int h[512], sc2[512], c2[512], sp[256];
    const int t = threadIdx.x;
    const int b = blockIdx.x;
    const int beg = bstart[b], end = bstart[b + 1];
    const int cnt = end - beg;

    h[t] = 0; h[t + 256] = 0; c2[t] = 0; c2[t + 256] = 0;
    __syncthreads();
    for (int i = t; i < cnt; i += 256)
        atomicAdd(&h[bucketed[beg + i] >> 17], 1);
    __syncthreads();

    int a0 = h[2 * t], a1 = h[2 * t + 1];
    sp[t] = a0 + a1;
    __syncthreads();
    for (int o = 1; o < 256; o <<= 1) {
        int a = (t >= o) ? sp[t - o] : 0;
        __syncthreads();
        sp[t] += a;
        __syncthreads();
    }
    int ep = sp[t] - (a0 + a1);
    sc2[2 * t] = ep;
    sc2[2 * t + 1] = ep + a0;
    __syncthreads();

    const int d0 = b << 9;
#pragma unroll
    for (int k = t; k < 512; k += 256) {
        int d = d0 + k;
        if (d < NN) off[d] = beg + sc2[k];
    }

    for (int i = t; i < cnt; i += 256) {
        unsigned int v = bucketed[beg + i];
        int ld = v >> 17;
        int r = atomicAdd(&c2[ld], 1);
        srcs[beg + sc2[ld] + r] = (int)(v & 0x1FFFFu);
    }
}

// ======================= weight conversion (all 3 layers, one launch) =======================
__global__ void k_cvtw3(const float* __restrict__ W0, const float* __restrict__ W1,
                        const float* __restrict__ W2, unsigned short* __restrict__ Wb) {
    int i = blockIdx.x * 256 + threadIdx.x;   // 49152 elements
    const float* W = (i < 16384) ? W0 : (i < 32768) ? W1 : W2;
    Wb[i] = f2bf(W[i & 16383]);
}

// ======================= MFMA GEMM: H = X @ W^T, fused BN-affine/relu/cvt + AS/AD ===========
// MODE 0: plain fp32 read; MODE 1: BN affine (computed in-kernel from raw stats) + relu
template<int MODE>
__global__ __launch_bounds__(256) void k_mfma(
    const float* __restrict__ Xf, const unsigned short* __restrict__ Wb,
    const float* __restrict__ gsum, const float* __restrict__ gsq,
    const float* __restrict__ gamma, const float* __restrict__ beta,
    const float* __restrict__ asrc, const float* __restrict__ adst,
    unsigned short* __restrict__ Hb, float* __restrict__ AS, float* __restrict__ AD)
{
    __shared__ float hst[4][16][132];
    __shared__ float scale_s[128], shift_s[128];
    const int t    = threadIdx.x;
    const int w    = t >> 6;
    const int lane = t & 63;
    const int c    = lane & 15;
    const int q    = lane >> 4;
    const int r0   = blockIdx.x * 64 + w * 16;
    const int row  = r0 + c;

    if (MODE) {
        // BN final stage fused here: per-column affine from raw sums (once per block)
        if (t < 128) {
            float mu  = gsum[t] * (1.f / NN);
            float var = gsq[t] * (1.f / NN) - mu * mu;
            float sc  = gamma[t] * rsqrtf(var + 1e-5f);
            scale_s[t] = sc;
            shift_s[t] = beta[t] - mu * sc;
        }
        __syncthreads();
    }

    union { uint4 u; bf16x8 v; } Af[4];
    if (row < NN) {
        const float* xp = Xf + ((size_t)row << 7) + (q << 3);
#pragma unroll
        for (int k0 = 0; k0 < 4; ++k0) {
            float4 a = *(const float4*)(xp + (k0 << 5));
            float4 b = *(const float4*)(xp + (k0 << 5) + 4);
            if (MODE) {
                const int kb = (k0 << 5) + (q << 3);
                float4 sA = *(const float4*)&scale_s[kb];
                float4 sB = *(const float4*)&scale_s[kb + 4];
                float4 hA = *(const float4*)&shift_s[kb];
                float4 hB = *(const float4*)&shift_s[kb + 4];
                a.x = fmaxf(0.f, fmaf(a.x, sA.x, hA.x));
                a.y = fmaxf(0.f, fmaf(a.y, sA.y, hA.y));
                a.z = fmaxf(0.f, fmaf(a.z, sA.z, hA.z));
                a.w = fmaxf(0.f, fmaf(a.w, sA.w, hA.w));
                b.x = fmaxf(0.f, fmaf(b.x, sB.x, hB.x));
                b.y = fmaxf(0.f, fmaf(b.y, sB.y, hB.y));
                b.z = fmaxf(0.f, fmaf(b.z, sB.z, hB.z));
                b.w = fmaxf(0.f, fmaf(b.w, sB.w, hB.w));
            }
            Af[k0].u.x = pk2(a.x, a.y);
            Af[k0].u.y = pk2(a.z, a.w);
            Af[k0].u.z = pk2(b.x, b.y);
            Af[k0].u.w = pk2(b.z, b.w);
        }
    } else {
#pragma unroll
        for (int k0 = 0; k0 < 4; ++k0) Af[k0].u = make_uint4(0, 0, 0, 0);
    }

    f32x4 acc[8];
#pragma unroll
    for (int nt = 0; nt < 8; ++nt) acc[nt] = (f32x4){0.f, 0.f, 0.f, 0.f};

#pragma unroll
    for (int nt = 0; nt < 8; ++nt) {
        union { uint4 u; bf16x8 v; } Bf[4];
        const size_t bbase = ((size_t)(nt * 16 + c) << 7) + (q << 3);
#pragma unroll
        for (int k0 = 0; k0 < 4; ++k0)
            Bf[k0].u = *(const uint4*)(Wb + bbase + (k0 << 5));
#pragma unroll
        for (int k0 = 0; k0 < 4; ++k0)
            acc[nt] = __builtin_amdgcn_mfma_f32_16x16x32_bf16(Af[k0].v, Bf[k0].v, acc[nt], 0, 0, 0);
    }

    // fused AS/AD; C/D layout col=lane&15, row=q*4+reg
    float ps[4] = {0.f, 0.f, 0.f, 0.f}, pd[4] = {0.f, 0.f, 0.f, 0.f};
#pragma unroll
    for (int nt = 0; nt < 8; ++nt) {
        float av = asrc[nt * 16 + c];
        float dv = adst[nt * 16 + c];
#pragma unroll
        for (int r = 0; r < 4; ++r) {
            ps[r] = fmaf(acc[nt][r], av, ps[r]);
            pd[r] = fmaf(acc[nt][r], dv, pd[r]);
        }
    }
#pragma unroll
    for (int m = 1; m < 16; m <<= 1) {
#pragma unroll
        for (int r = 0; r < 4; ++r) { ps[r] += __shfl_xor(ps[r], m); pd[r] += __shfl_xor(pd[r], m); }
    }
    if (c == 0) {
#pragma unroll
        for (int r = 0; r < 4; ++r) {
            int grow = r0 + q * 4 + r;
            if (grow < NN) { AS[grow] = ps[r]; AD[grow] = pd[r]; }
        }
    }

    // H store via LDS transpose, pk-cvt to bf16
#pragma unroll
    for (int nt = 0; nt < 8; ++nt)
#pragma unroll
        for (int r = 0; r < 4; ++r)
            hst[w][q * 4 + r][nt * 16 + c] = acc[nt][r];
    __syncthreads();
    {
        const int orow = lane >> 2, seg = lane & 3;
        const int grow = r0 + orow;
        if (grow < NN) {
#pragma unroll
            for (int i = 0; i < 4; ++i) {
                float4 a = *(const float4*)&hst[w][orow][seg * 32 + i * 8];
                float4 b = *(const float4*)&hst[w][orow][seg * 32 + i * 8 + 4];
                uint4 o;
                o.x = pk2(a.x, a.y); o.y = pk2(a.z, a.w);
                o.z = pk2(b.x, b.y); o.w = pk2(b.z, b.w);
                *(uint4*)(Hb + ((size_t)grow << 7) + seg * 32 + i * 8) = o;
            }
        }
    }
}

// ======================= per-dst softmax + aggregation (single pass) =======================
// v4: weights inline again (k_ew cost > its savings), but DECOUPLED: src and wgt travel
// via separate __shfl's, so Hb gather addresses depend only on the coalesced srcs load
// while the AS-gather/leaky/exp chain overlaps with gather latency. Manual 4/2/1 unroll
// ladder raises per-wave MLP to up to 4 KB in flight (the compiler cannot unroll the
// runtime-trip-count loop itself).
__device__ __forceinline__ void fma8(float* acc, uint4 u, float w) {
    acc[0] = fmaf(w, bflo(u.x), acc[0]);
    acc[1] = fmaf(w, bfhi(u.x), acc[1]);
    acc[2] = fmaf(w, bflo(u.y), acc[2]);
    acc[3] = fmaf(w, bfhi(u.y), acc[3]);
    acc[4] = fmaf(w, bflo(u.z), acc[4]);
    acc[5] = fmaf(w, bfhi(u.z), acc[5]);
    acc[6] = fmaf(w, bflo(u.w), acc[6]);
    acc[7] = fmaf(w, bfhi(u.w), acc[7]);
}

__global__ __launch_bounds__(256) void k_agg(
    const int* __restrict__ off, const int* __restrict__ srcs,
    const unsigned short* __restrict__ Hb, const float* __restrict__ AS,
    const float* __restrict__ AD, const float* __restrict__ bias,
    float* __restrict__ OUT)
{
    const int wid  = threadIdx.x >> 6;
    const int lane = threadIdx.x & 63;
    const int g    = lane >> 4;     // edge subgroup 0..3
    const int x16  = lane & 15;     // 16-lane column group
    const int n    = blockIdx.x * 4 + wid;
    const int beg = off[n], end = off[n + 1];
    const float adn = AD[n];

    float acc[8];
#pragma unroll
    for (int i = 0; i < 8; ++i) acc[i] = 0.f;
    float den = 0.f;

    for (int base = beg; base < end; base += 64) {
        int cnt = end - base; if (cnt > 64) cnt = 64;
        int s = 0; float wgt = 0.f;
        if (lane < cnt) {
            s = srcs[base + lane];
            float e = AS[s] + adn;              // random 4B gather (L2-resident, 400 KB)
            e = (e > 0.f) ? e : 0.2f * e;
            wgt = __expf(e);                    // this chain overlaps the Hb gathers below
        }
        den += wgt;
        const int rounds = (cnt + 3) >> 2;
        int j = 0;
        for (; j + 4 <= rounds; j += 4) {
            const int r0 = (j << 2) + g;
            int s0 = __shfl(s, r0);
            int s1 = __shfl(s, r0 + 4);
            int s2 = __shfl(s, r0 + 8);
            int s3 = __shfl(s, r0 + 12);
            uint4 u0 = *((const uint4*)(Hb + ((size_t)s0 << 7)) + x16);
            uint4 u1 = *((const uint4*)(Hb + ((size_t)s1 << 7)) + x16);
            uint4 u2 = *((const uint4*)(Hb + ((size_t)s2 << 7)) + x16);
            uint4 u3 = *((const uint4*)(Hb + ((size_t)s3 << 7)) + x16);
            float w0 = __shfl(wgt, r0);
            float w1 = __shfl(wgt, r0 + 4);
            float w2 = __shfl(wgt, r0 + 8);
            float w3 = __shfl(wgt, r0 + 12);
            fma8(acc, u0, w0);
            fma8(acc, u1, w1);
            fma8(acc, u2, w2);
            fma8(acc, u3, w3);
        }
        for (; j + 2 <= rounds; j += 2) {
            const int r0 = (j << 2) + g;
            int s0 = __shfl(s, r0);
            int s1 = __shfl(s, r0 + 4);
            uint4 u0 = *((const uint4*)(Hb + ((size_t)s0 << 7)) + x16);
            uint4 u1 = *((const uint4*)(Hb + ((size_t)s1 << 7)) + x16);
            float w0 = __shfl(wgt, r0);
            float w1 = __shfl(wgt, r0 + 4);
            fma8(acc, u0, w0);
            fma8(acc, u1, w1);
        }
        if (j < rounds) {
            const int r0 = (j << 2) + g;
            int s0 = __shfl(s, r0);
            uint4 u0 = *((const uint4*)(Hb + ((size_t)s0 << 7)) + x16);
            float w0 = __shfl(wgt, r0);
            fma8(acc, u0, w0);
        }
    }

    // reduce partial sums across the 4 edge subgroups; den across all 64 lanes
#pragma unroll
    for (int i = 0; i < 8; ++i) {
        acc[i] += __shfl_xor(acc[i], 16);
        acc[i] += __shfl_xor(acc[i], 32);
    }
#pragma unroll
    for (int o = 32; o; o >>= 1) den += __shfl_xor(den, o);
    float inv = 1.f / den;

    if (g == 0) {
        float4 b1 = *(const float4*)&bias[x16 << 3];
        float4 b2 = *(const float4*)&bias[(x16 << 3) + 4];
        float4 o1 = make_float4(fmaf(acc[0], inv, b1.x), fmaf(acc[1], inv, b1.y),
                                fmaf(acc[2], inv, b1.z), fmaf(acc[3], inv, b1.w));
        float4 o2 = make_float4(fmaf(acc[4], inv, b2.x), fmaf(acc[5], inv, b2.y),
                                fmaf(acc[6], inv, b2.z), fmaf(acc[7], inv, b2.w));
        float* op = OUT + ((size_t)n << 7) + (x16 << 3);
        *(float4*)op = o1;
        *(float4*)(op + 4) = o2;
    }
}

// ======================= batchnorm stats (raw sums; affine folded into k_mfma) ===========
__global__ void k_colsum(const float* __restrict__ Xf, float* __restrict__ gsum, float* __restrict__ gsq) {
    __shared__ float ls[256], lq[256];
    int t = threadIdx.x;
    int c = t & 127, half = t >> 7;
    float s = 0.f, q = 0.f;
    for (int r = blockIdx.x * 2 + half; r < NN; r += STAT_BLOCKS * 2) {
        float v = Xf[(size_t)r * 128 + c];
        s += v; q += v * v;
    }
    ls[t] = s; lq[t] = q;
    __syncthreads();
    if (t < 128) {
        atomicAdd(&gsum[c], ls[t] + ls[t + 128]);
        atomicAdd(&gsq[c],  lq[t] + lq[t + 128]);
    }
}

extern "C" void kernel_launch(void* const* d_in, const int* in_sizes, int n_in,
                              void* d_out, int out_size, void* d_ws, size_t ws_size,
                              hipStream_t stream)
{
    const float* x  = (const float*)d_in[0];
    const int*   ei = (const int*)d_in[1];
    const float* Wm[3]  = {(const float*)d_in[2], (const float*)d_in[6],  (const float*)d_in[10]};
    const float* Asr[3] = {(const float*)d_in[3], (const float*)d_in[7],  (const float*)d_in[11]};
    const float* Ads[3] = {(const float*)d_in[4], (const float*)d_in[8],  (const float*)d_in[12]};
    const float* Bs[3]  = {(const float*)d_in[5], (const float*)d_in[9],  (const float*)d_in[13]};
    const float* gam[2] = {(const float*)d_in[14], (const float*)d_in[16]};
    const float* bet[2] = {(const float*)d_in[15], (const float*)d_in[17]};

    char* p = (char*)d_ws;
    auto carve = [&](size_t bytes) -> char* {
        char* r = p;
        p += (bytes + 255) & ~(size_t)255;
        return r;
    };
    int*   off_   = (int*)carve((size_t)(NN + 1) * 4);
    int*   srcs   = (int*)carve((size_t)ET * 4);
    unsigned int* bucketed = (unsigned int*)carve((size_t)ET * 4);
    int*   btot   = (int*)carve(256 * 4);          // 1024 B, followed immediately by...
    float* gstat  = (float*)carve(4 * 128 * 4);    // gsum0,gsq0,gsum1,gsq1 (2048 B) — one memset
    int*   bstart = (int*)carve(260 * 4);
    int*   bcur   = (int*)carve(256 * 4);
    unsigned short* Hb  = (unsigned short*)carve((size_t)NP * 128 * 2);
    unsigned short* Wb  = (unsigned short*)carve((size_t)3 * 16384 * 2);  // contiguous 3 layers
    float* AS    = (float*)carve((size_t)NN * 4);
    float* AD    = (float*)carve((size_t)NN * 4);

    float* OUTf = (float*)d_out;   // fp32 intermediate lives in d_out (fully rewritten)

    // zero btot + all 4 stat vectors in one shot (they are carved adjacently)
    (void)hipMemsetAsync(btot, 0, 256 * 4 + 4 * 128 * 4, stream);

    // CSR build (bucket sort)
    k_bcount<<<256, 256, 0, stream>>>(ei, btot);
    k_bscan<<<1, 256, 0, stream>>>(btot, bstart, bcur, off_);
    k_bucket<<<(ET + TILE - 1) / TILE, 256, 0, stream>>>(ei, bcur, bucketed);
    k_csr<<<NBKT, 256, 0, stream>>>(bucketed, bstart, off_, srcs);

    // weight conversions (single launch)
    k_cvtw3<<<192, 256, 0, stream>>>(Wm[0], Wm[1], Wm[2], Wb);

    const int MFMA_GRID = NP / 64;

    // layer 0
    k_mfma<0><<<MFMA_GRID, 256, 0, stream>>>(x, Wb, nullptr, nullptr, nullptr, nullptr,
                                             Asr[0], Ads[0], Hb, AS, AD);
    k_agg<<<NN / 4, 256, 0, stream>>>(off_, srcs, Hb, AS, AD, Bs[0], OUTf);
    k_colsum<<<STAT_BLOCKS, 256, 0, stream>>>(OUTf, gstat, gstat + 128);

    // layer 1 (BN affine computed inside k_mfma from raw sums)
    k_mfma<1><<<MFMA_GRID, 256, 0, stream>>>(OUTf, Wb + 16384, gstat, gstat + 128,
                                             gam[0], bet[0], Asr[1], Ads[1], Hb, AS, AD);
    k_agg<<<NN / 4, 256, 0, stream>>>(off_, srcs, Hb, AS, AD, Bs[1], OUTf);
    k_colsum<<<STAT_BLOCKS, 256, 0, stream>>>(OUTf, gstat + 256, gstat + 384);

    // layer 2 (k_agg writes final fp32 output into d_out)
    k_mfma<1><<<MFMA_GRID, 256, 0, stream>>>(OUTf, Wb + 32768, gstat + 256, gstat + 384,
                                             gam[1], bet[1], Asr[2], Ads[2], Hb, AS, AD);
    k_agg<<<NN / 4, 256, 0, stream>>>(off_, srcs, Hb, AS, AD, Bs[2], OUTf);
}